// Round 11
// baseline (199.522 us; speedup 1.0000x reference)
//
#include <hip/hip_runtime.h>

#define T_TOK 512
#define HDIM 2048
#define NEXP 8
#define IDIM 4096

typedef float f32x4 __attribute__((ext_vector_type(4)));
typedef __bf16 bf16x8 __attribute__((ext_vector_type(8)));
typedef unsigned short ushort8 __attribute__((ext_vector_type(8)));

static __device__ __forceinline__ unsigned short f2bf(float f) {
    unsigned int u = __float_as_uint(f);
    u = (u + 0x7fffu + ((u >> 16) & 1u)) >> 16;
    return (unsigned short)u;
}

static __device__ __forceinline__ bf16x8 cvt8(const f32x4 lo, const f32x4 hi) {
    bf16x8 r;
#pragma unroll
    for (int q = 0; q < 4; ++q) { r[q] = (__bf16)lo[q]; r[q + 4] = (__bf16)hi[q]; }
    return r;
}

// async global->LDS, 16 B/lane; LDS dest = wave-uniform base + lane*16,
// global source is PER-LANE (carries the granule swizzle)
static __device__ __forceinline__ void gload_lds16(const void* g, void* l) {
    auto gp = reinterpret_cast<const unsigned int __attribute__((address_space(1)))*>(
        reinterpret_cast<unsigned long long>(g));
    auto lp = reinterpret_cast<unsigned int __attribute__((address_space(3)))*>(
        static_cast<unsigned int>(reinterpret_cast<unsigned long long>(l)));
    __builtin_amdgcn_global_load_lds(gp, lp, 16, 0, 0);
}

// ---------------- routing ------------------------------------------------------
__global__ void k_route(const float* __restrict__ logits,
                        int* __restrict__ off, int* __restrict__ tok,
                        float* __restrict__ scale) {
    __shared__ int cnt[NEXP], cur[NEXP];
    const int t = threadIdx.x;
    if (t < NEXP) cnt[t] = 0;
    __syncthreads();
    float m = logits[t * NEXP];
    int a = 0;
#pragma unroll
    for (int j = 1; j < NEXP; ++j) {
        float v = logits[t * NEXP + j];
        if (v > m) { m = v; a = j; }
    }
    scale[t] = 1.f / (1.f + __expf(-m));
    atomicAdd(&cnt[a], 1);
    __syncthreads();
    if (t == 0) {
        int o = 0;
        for (int e = 0; e < NEXP; ++e) { off[e] = o; cur[e] = o; o += cnt[e]; }
        off[NEXP] = o;
    }
    __syncthreads();
    int r = atomicAdd(&cur[a], 1);
    tok[r] = t;
}

// ---------------- gather + scale + bf16 ---------------------------------------
__global__ void k_gather(const float* __restrict__ x, const int* __restrict__ tok,
                         const float* __restrict__ scale,
                         unsigned short* __restrict__ xs) {
    const int pos = blockIdx.x;
    const int t = tok[pos];
    const float s = scale[t];
    const int c = threadIdx.x * 8;
    const float4* src = (const float4*)(x + (size_t)t * HDIM + c);
    float4 v0 = src[0], v1 = src[1];
    ushort8 o;
    o[0] = f2bf(v0.x * s); o[1] = f2bf(v0.y * s);
    o[2] = f2bf(v0.z * s); o[3] = f2bf(v0.w * s);
    o[4] = f2bf(v1.x * s); o[5] = f2bf(v1.y * s);
    o[6] = f2bf(v1.z * s); o[7] = f2bf(v1.w * s);
    *(ushort8*)(xs + (size_t)pos * HDIM + c) = o;
}

// ---------------- GEMM1: gate/up + SiLU ----------------------------------------
// 512 blocks: expert = bid&7 (one expert per XCD), ntile = bid>>3 (64 of BN=64).
// 512 thr = 8 waves (2x4); wave owns 64x16 of the 128x64 C-tile (x2 mats).
// BK=64, single-buffer LDS 48K. K-phase STAGGERED per block: ks=(i+bid*13)&31
// so instantaneous chip-wide addresses cover all k-offsets (HBM channel balance).
__global__ void __launch_bounds__(512, 4)
k_moe1(const unsigned short* __restrict__ xs,
       const float* __restrict__ w1,
       const float* __restrict__ w3,
       const int* __restrict__ off,
       unsigned short* __restrict__ hbuf) {
    __shared__ char smem[49152];

    const int tid = threadIdx.x;
    const int w = tid >> 6, l = tid & 63;
    const int wr = w >> 2, wc = w & 3;
    const int e = blockIdx.x & 7;
    const int n0 = (blockIdx.x >> 3) * 64;
    const int ks0 = (blockIdx.x * 13) & 31;
    const int pos_beg = off[e], pos_end = off[e + 1];

    const char* w1b = (const char*)(w1 + (size_t)e * IDIM * HDIM);
    const char* w3b = (const char*)(w3 + (size_t)e * IDIM * HDIM);
    const char* xsb = (const char*)xs;

    const int ia = w * 2;                       // instr ids ia, ia+1
    const int arow_off = l >> 3;                // A: row = i*8 + (l>>3)
    const int asw = ((l & 7) ^ (l >> 3)) << 4;  // A source granule swizzle
    const int brow_off = l >> 4;                // B: row = i*4 + (l>>4)

    for (int m0 = pos_beg; m0 < pos_end; m0 += 128) {
        f32x4 accG[4], accU[4];
#pragma unroll
        for (int i = 0; i < 4; ++i) { accG[i] = (f32x4){0,0,0,0}; accU[i] = (f32x4){0,0,0,0}; }

#pragma unroll 1
        for (int it = 0; it < HDIM / 64; ++it) {
            const int ks = (it + ks0) & 31;     // staggered K phase
            const int k0 = ks * 64;
            // stage A tile: 16 x 1KB instrs (rows i*8..i*8+7 each)
#pragma unroll
            for (int j = 0; j < 2; ++j) {
                const int i = ia + j;
                int gr = m0 + i * 8 + arow_off; if (gr > T_TOK - 1) gr = T_TOK - 1;
                gload_lds16(xsb + (size_t)gr * (HDIM * 2) + k0 * 2 + asw, smem + i * 1024);
            }
            // stage B tiles: 16 x 1KB instrs each (rows i*4..i*4+3, 256B rows)
#pragma unroll
            for (int j = 0; j < 2; ++j) {
                const int i = ia + j;
                const int r = i * 4 + brow_off;
                const size_t so = (size_t)(n0 + r) * (HDIM * 4) + k0 * 4 +
                                  (((l & 15) << 4) ^ ((r & 7) << 4));
                gload_lds16(w1b + so, smem + 16384 + i * 1024);
                gload_lds16(w3b + so, smem + 32768 + i * 1024);
            }
            __syncthreads();   // drains vmcnt: staged tiles ready

#pragma unroll
            for (int kk = 0; kk < 2; ++kk) {
                bf16x8 a[4];
#pragma unroll
                for (int fm = 0; fm < 4; ++fm) {
                    const int row = wr * 64 + fm * 16 + (l & 15);
                    const int kb = (kk * 64 + ((l >> 4) << 4)) ^ ((l & 7) << 4);
                    a[fm] = *(const bf16x8*)(smem + row * 128 + kb);
                }
                const int rB = wc * 16 + (l & 15);
                const int p0 = (kk * 128 + ((l >> 4) << 5)) ^ ((l & 7) << 4);
                const char* pg = smem + 16384 + rB * 256;
                const char* pu = smem + 32768 + rB * 256;
                f32x4 g0 = *(const f32x4*)(pg + p0);
                f32x4 g1 = *(const f32x4*)(pg + (p0 ^ 16));
                f32x4 u0 = *(const f32x4*)(pu + p0);
                f32x4 u1 = *(const f32x4*)(pu + (p0 ^ 16));
                bf16x8 bg = cvt8(g0, g1);
                bf16x8 bu = cvt8(u0, u1);
#pragma unroll
                for (int fm = 0; fm < 4; ++fm) {
                    accG[fm] = __builtin_amdgcn_mfma_f32_16x16x32_bf16(
                        a[fm], bg, accG[fm], 0, 0, 0);
                    accU[fm] = __builtin_amdgcn_mfma_f32_16x16x32_bf16(
                        a[fm], bu, accU[fm], 0, 0, 0);
                }
            }
            __syncthreads();   // all ds_reads done before next stage overwrites
        }

        // epilogue: h = silu(gate) * up -> bf16  (C: col=l&15, row=(l>>4)*4+r)
#pragma unroll
        for (int fm = 0; fm < 4; ++fm)
#pragma unroll
            for (int r = 0; r < 4; ++r) {
                const int pos = m0 + wr * 64 + fm * 16 + (l >> 4) * 4 + r;
                if (pos < pos_end) {
                    const float gv = accG[fm][r];
                    const float uv = accU[fm][r];
                    const float hv = gv / (1.f + __expf(-gv)) * uv;
                    hbuf[(size_t)pos * IDIM + n0 + wc * 16 + (l & 15)] = f2bf(hv);
                }
            }
    }
}

// ---------------- GEMM2: down proj + scatter -----------------------------------
// 1024 blocks: expert = bid&7, ntile = bid>>3 (128 of BN=16). 256 thr (4 waves),
// C-tile 128x16, K=4096, BK=64, staggered K phase.
__global__ void __launch_bounds__(256, 4)
k_moe2(const unsigned short* __restrict__ hbuf,
       const float* __restrict__ w2,
       const int* __restrict__ off,
       const int* __restrict__ tok,
       float* __restrict__ out) {
    __shared__ char smem[20480];

    const int tid = threadIdx.x;
    const int w = tid >> 6, l = tid & 63;
    const int e = blockIdx.x & 7;
    const int n0 = (blockIdx.x >> 3) * 16;
    const int ks0 = (blockIdx.x * 13) & 63;
    const int pos_beg = off[e], pos_end = off[e + 1];
    const char* w2b = (const char*)(w2 + (size_t)e * HDIM * IDIM);
    const char* hb  = (const char*)hbuf;

    const int ia = w * 4;                       // A instrs ia..ia+3
    const int arow_off = l >> 3;
    const int asw = ((l & 7) ^ (l >> 3)) << 4;
    const int brow_off = l >> 4;                // B instr w: rows w*4..w*4+3

    for (int m0 = pos_beg; m0 < pos_end; m0 += 128) {
        f32x4 acc[2];
        acc[0] = (f32x4){0,0,0,0}; acc[1] = (f32x4){0,0,0,0};

#pragma unroll 1
        for (int it = 0; it < IDIM / 64; ++it) {
            const int ks = (it + ks0) & 63;
            const int k0 = ks * 64;
#pragma unroll
            for (int j = 0; j < 4; ++j) {
                const int i = ia + j;
                int gr = m0 + i * 8 + arow_off; if (gr > T_TOK - 1) gr = T_TOK - 1;
                gload_lds16(hb + (size_t)gr * (IDIM * 2) + k0 * 2 + asw, smem + i * 1024);
            }
            {
                const int r = w * 4 + brow_off;
                const size_t so = (size_t)(n0 + r) * (IDIM * 4) + k0 * 4 +
                                  (((l & 15) << 4) ^ ((r & 7) << 4));
                gload_lds16(w2b + so, smem + 16384 + w * 1024);
            }
            __syncthreads();

#pragma unroll
            for (int kk = 0; kk < 2; ++kk) {
                const int rB = l & 15;
                const int p0 = (kk * 128 + ((l >> 4) << 5)) ^ ((l & 7) << 4);
                const char* pb = smem + 16384 + rB * 256;
                f32x4 b0 = *(const f32x4*)(pb + p0);
                f32x4 b1 = *(const f32x4*)(pb + (p0 ^ 16));
                bf16x8 bb = cvt8(b0, b1);
#pragma unroll
                for (int fm = 0; fm < 2; ++fm) {
                    const int row = w * 32 + fm * 16 + (l & 15);
                    const int kb = (kk * 64 + ((l >> 4) << 4)) ^ ((l & 7) << 4);
                    bf16x8 a = *(const bf16x8*)(smem + row * 128 + kb);
                    acc[fm] = __builtin_amdgcn_mfma_f32_16x16x32_bf16(a, bb, acc[fm], 0, 0, 0);
                }
            }
            __syncthreads();
        }

#pragma unroll
        for (int fm = 0; fm < 2; ++fm)
#pragma unroll
            for (int r = 0; r < 4; ++r) {
                const int pos = m0 + w * 32 + fm * 16 + (l >> 4) * 4 + r;
                if (pos < pos_end) {
                    const int t = tok[pos];
                    out[(size_t)t * HDIM + n0 + (l & 15)] = acc[fm][r];
                }
            }
    }
}

extern "C" void kernel_launch(void* const* d_in, const int* in_sizes, int n_in,
                              void* d_out, int out_size, void* d_ws, size_t ws_size,
                              hipStream_t stream) {
    const float* x      = (const float*)d_in[0];
    const float* logits = (const float*)d_in[1];
    const float* w1     = (const float*)d_in[2];
    const float* w3     = (const float*)d_in[3];
    const float* w2     = (const float*)d_in[4];
    float* out = (float*)d_out;

    char* ws = (char*)d_ws;
    int* off   = (int*)ws;                          // 9 ints
    int* tok   = (int*)(ws + 64);                   // 512 ints
    float* scl = (float*)(ws + 64 + 2048);          // 512 floats
    unsigned short* xs   = (unsigned short*)(ws + 8192);                             // 2 MiB
    unsigned short* hbuf = (unsigned short*)(ws + 8192 + (size_t)T_TOK * HDIM * 2);  // 4 MiB

    k_route<<<1, T_TOK, 0, stream>>>(logits, off, tok, scl);
    k_gather<<<T_TOK, 256, 0, stream>>>(x, tok, scl, xs);
    k_moe1<<<NEXP * (IDIM / 64), 512, 0, stream>>>(xs, w1, w3, off, hbuf);
    k_moe2<<<NEXP * (HDIM / 16), 256, 0, stream>>>(hbuf, w2, off, tok, out);
}

// Round 14
// 185.032 us; speedup vs baseline: 1.0783x; 1.0783x over previous
//
#include <hip/hip_runtime.h>

#define T_TOK 512
#define HDIM 2048
#define NEXP 8
#define IDIM 4096

typedef float f32x4 __attribute__((ext_vector_type(4)));
typedef __bf16 bf16x8 __attribute__((ext_vector_type(8)));
typedef unsigned short ushort8 __attribute__((ext_vector_type(8)));

static __device__ __forceinline__ unsigned short f2bf(float f) {
    unsigned int u = __float_as_uint(f);
    u = (u + 0x7fffu + ((u >> 16) & 1u)) >> 16;
    return (unsigned short)u;
}

static __device__ __forceinline__ bf16x8 cvt8(const f32x4 lo, const f32x4 hi) {
    bf16x8 r;
#pragma unroll
    for (int q = 0; q < 4; ++q) { r[q] = (__bf16)lo[q]; r[q + 4] = (__bf16)hi[q]; }
    return r;
}

// async global->LDS, 16 B/lane; LDS dest = wave-uniform base + lane*16,
// global source is PER-LANE (carries the granule swizzle)
static __device__ __forceinline__ void gload_lds16(const void* g, void* l) {
    auto gp = reinterpret_cast<const unsigned int __attribute__((address_space(1)))*>(
        reinterpret_cast<unsigned long long>(g));
    auto lp = reinterpret_cast<unsigned int __attribute__((address_space(3)))*>(
        static_cast<unsigned int>(reinterpret_cast<unsigned long long>(l)));
    __builtin_amdgcn_global_load_lds(gp, lp, 16, 0, 0);
}

// non-temporal variant (aux = NT bit): weights are single-use per launch; NT
// keeps them OUT of L3 so the HBM miss stream stays fully sequential
// (DRAM page streaming) instead of L3-hit-interleaved scatter.
static __device__ __forceinline__ void gload_lds16_nt(const void* g, void* l) {
    auto gp = reinterpret_cast<const unsigned int __attribute__((address_space(1)))*>(
        reinterpret_cast<unsigned long long>(g));
    auto lp = reinterpret_cast<unsigned int __attribute__((address_space(3)))*>(
        static_cast<unsigned int>(reinterpret_cast<unsigned long long>(l)));
    __builtin_amdgcn_global_load_lds(gp, lp, 16, 0, 2 /*NT*/);
}

// ---------------- routing ------------------------------------------------------
__global__ void k_route(const float* __restrict__ logits,
                        int* __restrict__ off, int* __restrict__ tok,
                        float* __restrict__ scale) {
    __shared__ int cnt[NEXP], cur[NEXP];
    const int t = threadIdx.x;
    if (t < NEXP) cnt[t] = 0;
    __syncthreads();
    float m = logits[t * NEXP];
    int a = 0;
#pragma unroll
    for (int j = 1; j < NEXP; ++j) {
        float v = logits[t * NEXP + j];
        if (v > m) { m = v; a = j; }
    }
    scale[t] = 1.f / (1.f + __expf(-m));
    atomicAdd(&cnt[a], 1);
    __syncthreads();
    if (t == 0) {
        int o = 0;
        for (int e = 0; e < NEXP; ++e) { off[e] = o; cur[e] = o; o += cnt[e]; }
        off[NEXP] = o;
    }
    __syncthreads();
    int r = atomicAdd(&cur[a], 1);
    tok[r] = t;
}

// ---------------- gather + scale + bf16 ---------------------------------------
__global__ void k_gather(const float* __restrict__ x, const int* __restrict__ tok,
                         const float* __restrict__ scale,
                         unsigned short* __restrict__ xs) {
    const int pos = blockIdx.x;
    const int t = tok[pos];
    const float s = scale[t];
    const int c = threadIdx.x * 8;
    const float4* src = (const float4*)(x + (size_t)t * HDIM + c);
    float4 v0 = src[0], v1 = src[1];
    ushort8 o;
    o[0] = f2bf(v0.x * s); o[1] = f2bf(v0.y * s);
    o[2] = f2bf(v0.z * s); o[3] = f2bf(v0.w * s);
    o[4] = f2bf(v1.x * s); o[5] = f2bf(v1.y * s);
    o[6] = f2bf(v1.z * s); o[7] = f2bf(v1.w * s);
    *(ushort8*)(xs + (size_t)pos * HDIM + c) = o;
}

// ---------------- GEMM1: gate/up + SiLU ----------------------------------------
// 512 blocks: expert = bid&7 (one expert per XCD), ntile = bid>>3 (64 of BN=64).
// 512 thr = 8 waves (2x4); wave owns 64x16 of the 128x64 C-tile (x2 mats).
// BK=64, single-buffer LDS 48K, staggered K phase, NT weight staging.
__global__ void __launch_bounds__(512, 4)
k_moe1(const unsigned short* __restrict__ xs,
       const float* __restrict__ w1,
       const float* __restrict__ w3,
       const int* __restrict__ off,
       unsigned short* __restrict__ hbuf) {
    __shared__ char smem[49152];

    const int tid = threadIdx.x;
    const int w = tid >> 6, l = tid & 63;
    const int wr = w >> 2, wc = w & 3;
    const int e = blockIdx.x & 7;
    const int n0 = (blockIdx.x >> 3) * 64;
    const int ks0 = (blockIdx.x * 13) & 31;
    const int pos_beg = off[e], pos_end = off[e + 1];

    const char* w1b = (const char*)(w1 + (size_t)e * IDIM * HDIM);
    const char* w3b = (const char*)(w3 + (size_t)e * IDIM * HDIM);
    const char* xsb = (const char*)xs;

    const int ia = w * 2;                       // instr ids ia, ia+1
    const int arow_off = l >> 3;                // A: row = i*8 + (l>>3)
    const int asw = ((l & 7) ^ (l >> 3)) << 4;  // A source granule swizzle
    const int brow_off = l >> 4;                // B: row = i*4 + (l>>4)

    for (int m0 = pos_beg; m0 < pos_end; m0 += 128) {
        f32x4 accG[4], accU[4];
#pragma unroll
        for (int i = 0; i < 4; ++i) { accG[i] = (f32x4){0,0,0,0}; accU[i] = (f32x4){0,0,0,0}; }

#pragma unroll 1
        for (int it = 0; it < HDIM / 64; ++it) {
            const int ks = (it + ks0) & 31;     // staggered K phase
            const int k0 = ks * 64;
            // stage A tile: 16 x 1KB instrs (rows i*8..i*8+7 each) — cached
#pragma unroll
            for (int j = 0; j < 2; ++j) {
                const int i = ia + j;
                int gr = m0 + i * 8 + arow_off; if (gr > T_TOK - 1) gr = T_TOK - 1;
                gload_lds16(xsb + (size_t)gr * (HDIM * 2) + k0 * 2 + asw, smem + i * 1024);
            }
            // stage B tiles — NON-TEMPORAL (single-use stream, keep out of L3)
#pragma unroll
            for (int j = 0; j < 2; ++j) {
                const int i = ia + j;
                const int r = i * 4 + brow_off;
                const size_t so = (size_t)(n0 + r) * (HDIM * 4) + k0 * 4 +
                                  (((l & 15) << 4) ^ ((r & 7) << 4));
                gload_lds16_nt(w1b + so, smem + 16384 + i * 1024);
                gload_lds16_nt(w3b + so, smem + 32768 + i * 1024);
            }
            __syncthreads();   // drains vmcnt: staged tiles ready

#pragma unroll
            for (int kk = 0; kk < 2; ++kk) {
                bf16x8 a[4];
#pragma unroll
                for (int fm = 0; fm < 4; ++fm) {
                    const int row = wr * 64 + fm * 16 + (l & 15);
                    const int kb = (kk * 64 + ((l >> 4) << 4)) ^ ((l & 7) << 4);
                    a[fm] = *(const bf16x8*)(smem + row * 128 + kb);
                }
                const int rB = wc * 16 + (l & 15);
                const int p0 = (kk * 128 + ((l >> 4) << 5)) ^ ((l & 7) << 4);
                const char* pg = smem + 16384 + rB * 256;
                const char* pu = smem + 32768 + rB * 256;
                f32x4 g0 = *(const f32x4*)(pg + p0);
                f32x4 g1 = *(const f32x4*)(pg + (p0 ^ 16));
                f32x4 u0 = *(const f32x4*)(pu + p0);
                f32x4 u1 = *(const f32x4*)(pu + (p0 ^ 16));
                bf16x8 bg = cvt8(g0, g1);
                bf16x8 bu = cvt8(u0, u1);
#pragma unroll
                for (int fm = 0; fm < 4; ++fm) {
                    accG[fm] = __builtin_amdgcn_mfma_f32_16x16x32_bf16(
                        a[fm], bg, accG[fm], 0, 0, 0);
                    accU[fm] = __builtin_amdgcn_mfma_f32_16x16x32_bf16(
                        a[fm], bu, accU[fm], 0, 0, 0);
                }
            }
            __syncthreads();   // all ds_reads done before next stage overwrites
        }

        // epilogue: h = silu(gate) * up -> bf16  (C: col=l&15, row=(l>>4)*4+r)
#pragma unroll
        for (int fm = 0; fm < 4; ++fm)
#pragma unroll
            for (int r = 0; r < 4; ++r) {
                const int pos = m0 + wr * 64 + fm * 16 + (l >> 4) * 4 + r;
                if (pos < pos_end) {
                    const float gv = accG[fm][r];
                    const float uv = accU[fm][r];
                    const float hv = gv / (1.f + __expf(-gv)) * uv;
                    hbuf[(size_t)pos * IDIM + n0 + wc * 16 + (l & 15)] = f2bf(hv);
                }
            }
    }
}

// ---------------- GEMM2: down proj + scatter -----------------------------------
// 1024 blocks: expert = bid&7, ntile = bid>>3 (128 of BN=16). 256 thr (4 waves),
// C-tile 128x16, K=4096, BK=64, staggered K phase. w2 stays CACHED (L3-warm).
__global__ void __launch_bounds__(256, 4)
k_moe2(const unsigned short* __restrict__ hbuf,
       const float* __restrict__ w2,
       const int* __restrict__ off,
       const int* __restrict__ tok,
       float* __restrict__ out) {
    __shared__ char smem[20480];

    const int tid = threadIdx.x;
    const int w = tid >> 6, l = tid & 63;
    const int e = blockIdx.x & 7;
    const int n0 = (blockIdx.x >> 3) * 16;
    const int ks0 = (blockIdx.x * 13) & 63;
    const int pos_beg = off[e], pos_end = off[e + 1];
    const char* w2b = (const char*)(w2 + (size_t)e * HDIM * IDIM);
    const char* hb  = (const char*)hbuf;

    const int ia = w * 4;                       // A instrs ia..ia+3
    const int arow_off = l >> 3;
    const int asw = ((l & 7) ^ (l >> 3)) << 4;
    const int brow_off = l >> 4;                // B instr w: rows w*4..w*4+3

    for (int m0 = pos_beg; m0 < pos_end; m0 += 128) {
        f32x4 acc[2];
        acc[0] = (f32x4){0,0,0,0}; acc[1] = (f32x4){0,0,0,0};

#pragma unroll 1
        for (int it = 0; it < IDIM / 64; ++it) {
            const int ks = (it + ks0) & 63;
            const int k0 = ks * 64;
#pragma unroll
            for (int j = 0; j < 4; ++j) {
                const int i = ia + j;
                int gr = m0 + i * 8 + arow_off; if (gr > T_TOK - 1) gr = T_TOK - 1;
                gload_lds16(hb + (size_t)gr * (IDIM * 2) + k0 * 2 + asw, smem + i * 1024);
            }
            {
                const int r = w * 4 + brow_off;
                const size_t so = (size_t)(n0 + r) * (IDIM * 4) + k0 * 4 +
                                  (((l & 15) << 4) ^ ((r & 7) << 4));
                gload_lds16(w2b + so, smem + 16384 + w * 1024);
            }
            __syncthreads();

#pragma unroll
            for (int kk = 0; kk < 2; ++kk) {
                const int rB = l & 15;
                const int p0 = (kk * 128 + ((l >> 4) << 5)) ^ ((l & 7) << 4);
                const char* pb = smem + 16384 + rB * 256;
                f32x4 b0 = *(const f32x4*)(pb + p0);
                f32x4 b1 = *(const f32x4*)(pb + (p0 ^ 16));
                bf16x8 bb = cvt8(b0, b1);
#pragma unroll
                for (int fm = 0; fm < 2; ++fm) {
                    const int row = w * 32 + fm * 16 + (l & 15);
                    const int kb = (kk * 64 + ((l >> 4) << 4)) ^ ((l & 7) << 4);
                    bf16x8 a = *(const bf16x8*)(smem + row * 128 + kb);
                    acc[fm] = __builtin_amdgcn_mfma_f32_16x16x32_bf16(a, bb, acc[fm], 0, 0, 0);
                }
            }
            __syncthreads();
        }

#pragma unroll
        for (int fm = 0; fm < 2; ++fm)
#pragma unroll
            for (int r = 0; r < 4; ++r) {
                const int pos = m0 + w * 32 + fm * 16 + (l >> 4) * 4 + r;
                if (pos < pos_end) {
                    const int t = tok[pos];
                    out[(size_t)t * HDIM + n0 + (l & 15)] = acc[fm][r];
                }
            }
    }
}

extern "C" void kernel_launch(void* const* d_in, const int* in_sizes, int n_in,
                              void* d_out, int out_size, void* d_ws, size_t ws_size,
                              hipStream_t stream) {
    const float* x      = (const float*)d_in[0];
    const float* logits = (const float*)d_in[1];
    const float* w1     = (const float*)d_in[2];
    const float* w3     = (const float*)d_in[3];
    const float* w2     = (const float*)d_in[4];
    float* out = (float*)d_out;

    char* ws = (char*)d_ws;
    int* off   = (int*)ws;                          // 9 ints
    int* tok   = (int*)(ws + 64);                   // 512 ints
    float* scl = (float*)(ws + 64 + 2048);          // 512 floats
    unsigned short* xs   = (unsigned short*)(ws + 8192);                             // 2 MiB
    unsigned short* hbuf = (unsigned short*)(ws + 8192 + (size_t)T_TOK * HDIM * 2);  // 4 MiB

    k_route<<<1, T_TOK, 0, stream>>>(logits, off, tok, scl);
    k_gather<<<T_TOK, 256, 0, stream>>>(x, tok, scl, xs);
    k_moe1<<<NEXP * (IDIM / 64), 512, 0, stream>>>(xs, w1, w3, off, hbuf);
    k_moe2<<<NEXP * (HDIM / 16), 256, 0, stream>>>(hbuf, w2, off, tok, out);
}